// Round 5
// baseline (564.414 us; speedup 1.0000x reference)
//
#include <hip/hip_runtime.h>
#include <cstdint>
#include <cstddef>

#define NN 200000
#define DD 256
#define HH 1024
#define OUTD 4002
#define LL 2001
#define GG 4096

#define ROWS_PB 128
#define STEPS 8
#define SLOTS_L 8
#define SLOTS_G 4

typedef unsigned short u16;
typedef short short8 __attribute__((ext_vector_type(8)));
typedef float f32x4 __attribute__((ext_vector_type(4)));

static __device__ __forceinline__ u16 f2bf(float f) {
  uint32_t u = __float_as_uint(f);
  uint32_t r = (u + 0x7FFFu + ((u >> 16) & 1u)) >> 16;
  return (u16)r;
}
static __device__ __forceinline__ float bf2f(u16 b) {
  return __uint_as_float(((uint32_t)b) << 16);
}

static __device__ __forceinline__ void gld_lds16(const void* g, void* l) {
  __builtin_amdgcn_global_load_lds((const __attribute__((address_space(1))) void*)g,
                                   (__attribute__((address_space(3))) void*)l,
                                   16, 0, 0);
}

// Raw barrier: LDS ops flushed, but GLOBAL loads stay in flight across it.
static __device__ __forceinline__ void barrier_nodrain() {
  asm volatile("s_waitcnt lgkmcnt(0)" ::: "memory");
  __builtin_amdgcn_s_barrier();
  __builtin_amdgcn_sched_barrier(0);
}

// ---------------- transpose W (K x Nc fp32) -> WT (Nc x K bf16) ----------------
__global__ __launch_bounds__(256) void transpose_bf16(const float* __restrict__ W,
                                                      u16* __restrict__ WT,
                                                      int K, int Nc) {
  __shared__ float tile[32][33];
  int nt = blockIdx.x * 32, kt = blockIdx.y * 32;
  int tx = threadIdx.x & 31, ty = threadIdx.x >> 5;
#pragma unroll
  for (int i = 0; i < 4; ++i) {
    int k = kt + ty + i * 8, n = nt + tx;
    tile[ty + i * 8][tx] = (k < K && n < Nc) ? W[(size_t)k * Nc + n] : 0.f;
  }
  __syncthreads();
#pragma unroll
  for (int i = 0; i < 4; ++i) {
    int n = nt + ty + i * 8, k = kt + tx;
    if (n < Nc && k < K) WT[(size_t)n * K + k] = f2bf(tile[tx][ty + i * 8]);
  }
}

// ---------------- per-graph row offsets via binary search ----------------
__global__ void graph_offsets(const int* __restrict__ idx, int* __restrict__ offs) {
  int g = blockIdx.x * blockDim.x + threadIdx.x;
  if (g > GG) return;
  int lo = 0, hi = NN;
  while (lo < hi) {
    int mid = (lo + hi) >> 1;
    if (idx[mid] < g) lo = mid + 1; else hi = mid;
  }
  offs[g] = lo;
}

// ---------------- fused: att-GEMM + segmented exp-sum pooling ----------------
__global__ __launch_bounds__(512, 8) void fused_pool(const float* __restrict__ h,
                                                     const u16* __restrict__ WT,
                                                     const float* __restrict__ bias,
                                                     const int* __restrict__ idx,
                                                     const int* __restrict__ offs,
                                                     float* __restrict__ PS_ss,
                                                     float* __restrict__ PS_ah) {
  __shared__ __align__(16) u16 At[2][16 * 256];   // 2 x 8KB
  __shared__ float accS[SLOTS_L * 256];           // 8KB
  __shared__ float accA[SLOTS_L * 256];           // 8KB
  __shared__ int lidx[ROWS_PB];

  const int tid = threadIdx.x;
  const int wave = tid >> 6, lane = tid & 63;
  const int rl = lane & 15, q = lane >> 4;
  const int b = blockIdx.x;
  const long row0 = (long)b * ROWS_PB;

  if (tid < ROWS_PB) {
    long r = row0 + tid;
    lidx[tid] = (r < NN) ? idx[r] : -1;
  }
  for (int i = tid; i < SLOTS_L * 256; i += 512) { accS[i] = 0.f; accA[i] = 0.f; }

  // B fragments (W_pool^T, L2-resident): features f0 = wave*32+rl, f1 = f0+16
  const int f0 = wave * 32 + rl, f1 = f0 + 16;
  short8 Bf0[8], Bf1[8];
  {
    const u16* wp0 = WT + (size_t)f0 * 256 + q * 8;
    const u16* wp1 = WT + (size_t)f1 * 256 + q * 8;
#pragma unroll
    for (int k0 = 0; k0 < 8; ++k0) {
      Bf0[k0] = *reinterpret_cast<const short8*>(wp0 + k0 * 32);
      Bf1[k0] = *reinterpret_cast<const short8*>(wp1 + k0 * 32);
    }
  }
  const float bv0 = bias[f0], bv1 = bias[f1];

  // staging mapping: thread -> row tr, elems te..te+7 (bf16, XOR-swizzled)
  const int tr = tid >> 5, te = (tid & 31) * 8;
  const int wbyte = tr * 512 + ((te * 2) ^ ((tr & 7) << 4));
  float4 pf0, pf1;
  auto issue = [&](int st) {
    long r = row0 + (long)st * 16 + tr;
    if (r >= NN) r = NN - 1;
    const float* p = h + r * 256 + te;
    pf0 = *reinterpret_cast<const float4*>(p);
    pf1 = *reinterpret_cast<const float4*>(p + 4);
  };
  auto commit = [&](int bufsel) {
    short8 w;
    w[0] = (short)f2bf(pf0.x); w[1] = (short)f2bf(pf0.y);
    w[2] = (short)f2bf(pf0.z); w[3] = (short)f2bf(pf0.w);
    w[4] = (short)f2bf(pf1.x); w[5] = (short)f2bf(pf1.y);
    w[6] = (short)f2bf(pf1.z); w[7] = (short)f2bf(pf1.w);
    *reinterpret_cast<short8*>((char*)&At[0][0] + bufsel * 8192 + wbyte) = w;
  };

  // hoisted LDS read offsets
  int afoff[8], hv0off[4], hv1off[4];
#pragma unroll
  for (int k0 = 0; k0 < 8; ++k0)
    afoff[k0] = rl * 512 + ((k0 * 64 + q * 16) ^ ((rl & 7) << 4));
#pragma unroll
  for (int reg = 0; reg < 4; ++reg) {
    int rloc = q * 4 + reg;
    hv0off[reg] = rloc * 512 + ((f0 * 2) ^ ((rloc & 7) << 4));
    hv1off[reg] = rloc * 512 + ((f1 * 2) ^ ((rloc & 7) << 4));
  }

  issue(0);
  commit(0);
  issue(1);
  barrier_nodrain();

  const int gfirst = lidx[0];
  int cur = -1;
  float ss0 = 0.f, ss1 = 0.f, ah0 = 0.f, ah1 = 0.f;

#pragma unroll
  for (int st = 0; st < STEPS; ++st) {
    const char* Ab = (const char*)&At[0][0] + (st & 1) * 8192;
    short8 af[8];
#pragma unroll
    for (int k0 = 0; k0 < 8; ++k0)
      af[k0] = *reinterpret_cast<const short8*>(Ab + afoff[k0]);
    f32x4 acc0 = {0.f, 0.f, 0.f, 0.f}, acc1 = {0.f, 0.f, 0.f, 0.f};
#pragma unroll
    for (int k0 = 0; k0 < 8; ++k0) {
      acc0 = __builtin_amdgcn_mfma_f32_16x16x32_bf16(af[k0], Bf0[k0], acc0, 0, 0, 0);
      acc1 = __builtin_amdgcn_mfma_f32_16x16x32_bf16(af[k0], Bf1[k0], acc1, 0, 0, 0);
    }
#pragma unroll
    for (int reg = 0; reg < 4; ++reg) {
      const int rloc = q * 4 + reg;
      const int gid = lidx[st * 16 + rloc];
      float z0 = acc0[reg] + bv0, z1 = acc1[reg] + bv1;
      float a0 = z0 / (1.f + __expf(-z0));
      float a1 = z1 / (1.f + __expf(-z1));
      float x0 = __expf(a0), x1 = __expf(a1);
      float hv0 = bf2f(*reinterpret_cast<const u16*>(Ab + hv0off[reg]));
      float hv1 = bf2f(*reinterpret_cast<const u16*>(Ab + hv1off[reg]));
      if (gid != cur) {
        if (cur >= 0) {
          int sl = cur - gfirst; if (sl >= SLOTS_L) sl = SLOTS_L - 1;
          atomicAdd(&accS[sl * 256 + f0], ss0);
          atomicAdd(&accA[sl * 256 + f0], ah0);
          atomicAdd(&accS[sl * 256 + f1], ss1);
          atomicAdd(&accA[sl * 256 + f1], ah1);
        }
        ss0 = ss1 = ah0 = ah1 = 0.f;
        cur = gid;
      }
      if (gid >= 0) {
        ss0 += x0; ah0 = __builtin_fmaf(x0, hv0, ah0);
        ss1 += x1; ah1 = __builtin_fmaf(x1, hv1, ah1);
      }
    }
    if (st + 1 < STEPS) {
      commit((st + 1) & 1);
      if (st + 2 < STEPS) issue(st + 2);
    }
    barrier_nodrain();
  }

  if (cur >= 0) {
    int sl = cur - gfirst; if (sl >= SLOTS_L) sl = SLOTS_L - 1;
    atomicAdd(&accS[sl * 256 + f0], ss0);
    atomicAdd(&accA[sl * 256 + f0], ah0);
    atomicAdd(&accS[sl * 256 + f1], ss1);
    atomicAdd(&accA[sl * 256 + f1], ah1);
  }
  __syncthreads();

  // write per-(graph, slot) partials (no atomics: slot unique per block)
  long lastrow = row0 + ROWS_PB - 1; if (lastrow >= NN) lastrow = NN - 1;
  const int glast = idx[lastrow];
  int gspan = glast - gfirst + 1; if (gspan > SLOTS_L) gspan = SLOTS_L;
  const int f = tid & 255, which = tid >> 8;
  for (int s = 0; s < gspan; ++s) {
    int g = gfirst + s;
    int osl = b - (offs[g] >> 7);
    if (osl < 0) osl = 0;
    if (osl >= SLOTS_G) osl = SLOTS_G - 1;
    float v = which ? accA[s * 256 + f] : accS[s * 256 + f];
    float* dst = which ? PS_ah : PS_ss;
    dst[((size_t)g * SLOTS_G + osl) * 256 + f] = v;
  }
}

// ---------------- finalize: hG = sum(AH)/sum(SS) ----------------
__global__ __launch_bounds__(256) void finalize_pool(const float* __restrict__ PS_ss,
                                                     const float* __restrict__ PS_ah,
                                                     const int* __restrict__ offs,
                                                     u16* __restrict__ hG) {
  int i = blockIdx.x * 256 + threadIdx.x;
  int g = i >> 8, f = i & 255;
  int s0 = offs[g], s1 = offs[g + 1];
  float o = 0.f;
  if (s1 > s0) {
    int b0 = s0 >> 7, b1 = (s1 - 1) >> 7;
    int nsl = b1 - b0 + 1; if (nsl > SLOTS_G) nsl = SLOTS_G;
    float ss = 0.f, ah = 0.f;
    for (int s = 0; s < nsl; ++s) {
      ss += PS_ss[((size_t)g * SLOTS_G + s) * 256 + f];
      ah += PS_ah[((size_t)g * SLOTS_G + s) * 256 + f];
    }
    o = ah / fmaxf(ss, 1e-12f);
  }
  hG[i] = f2bf(o);
}

// ---------------- bf16 MFMA GEMM, counted-vmcnt double-buffer, BK=32/64 ----------------
template <int SILU, int MODE, int BK>
__global__ __launch_bounds__(256) void gemm_bt(const u16* __restrict__ A,
                                               const u16* __restrict__ BT,
                                               const float* __restrict__ bias,
                                               u16* __restrict__ Cb,
                                               float* __restrict__ Cf,
                                               float* __restrict__ Ci,
                                               float* __restrict__ Cr,
                                               int M, int Nn, int K) {
  constexpr int NSUB = BK / 32;
  __shared__ __align__(16) u16 As[2][NSUB][128 * 32];
  __shared__ __align__(16) u16 Bs[2][NSUB][128 * 32];
  const int tid = threadIdx.x;
  const int wave = tid >> 6, lane = tid & 63;
  const int wr = wave >> 1, wc = wave & 1;
  const long bm = (long)blockIdx.y * 128;
  const long bn = (long)blockIdx.x * 128;

  const f32x4 zero = {0.f, 0.f, 0.f, 0.f};
  f32x4 acc[4][4];
#pragma unroll
  for (int i = 0; i < 4; ++i)
#pragma unroll
    for (int j = 0; j < 4; ++j) acc[i][j] = zero;

  const int rg = lane >> 2;
  const int kc = (lane & 3) * 8;
  const int rl = lane & 15;
  const int kk = (lane >> 4) * 8;
  const int nt = K / BK;

  auto stage = [&](int t, int buf) {
    const long k0 = (long)t * BK;
#pragma unroll
    for (int s = 0; s < NSUB; ++s) {
#pragma unroll
      for (int c = 0; c < 2; ++c) {
        int r = wave * 32 + c * 16;
        long rA = bm + r + rg; if (rA >= M) rA = M - 1;
        long rB = bn + r + rg; if (rB >= Nn) rB = Nn - 1;
        gld_lds16(A + rA * K + k0 + s * 32 + kc, &As[buf][s][r * 32]);
        gld_lds16(BT + rB * K + k0 + s * 32 + kc, &Bs[buf][s][r * 32]);
      }
    }
  };

  stage(0, 0);
  for (int t = 0; t < nt; ++t) {
    const int buf = t & 1;
    if (t + 1 < nt) {
      stage(t + 1, buf ^ 1);
      if constexpr (NSUB == 1) {
        asm volatile("s_waitcnt vmcnt(4)" ::: "memory");
      } else {
        asm volatile("s_waitcnt vmcnt(8)" ::: "memory");
      }
    } else {
      asm volatile("s_waitcnt vmcnt(0)" ::: "memory");
    }
    __builtin_amdgcn_s_barrier();
    __builtin_amdgcn_sched_barrier(0);

#pragma unroll
    for (int s = 0; s < NSUB; ++s) {
      short8 af[4], bfr[4];
#pragma unroll
      for (int mi = 0; mi < 4; ++mi)
        af[mi] = *reinterpret_cast<const short8*>(&As[buf][s][(wr * 64 + mi * 16 + rl) * 32 + kk]);
#pragma unroll
      for (int ni = 0; ni < 4; ++ni)
        bfr[ni] = *reinterpret_cast<const short8*>(&Bs[buf][s][(wc * 64 + ni * 16 + rl) * 32 + kk]);
#pragma unroll
      for (int mi = 0; mi < 4; ++mi)
#pragma unroll
        for (int ni = 0; ni < 4; ++ni)
          acc[mi][ni] = __builtin_amdgcn_mfma_f32_16x16x32_bf16(af[mi], bfr[ni], acc[mi][ni], 0, 0, 0);
    }

    asm volatile("s_waitcnt lgkmcnt(0)" ::: "memory");
    __builtin_amdgcn_s_barrier();
    __builtin_amdgcn_sched_barrier(0);
  }

#pragma unroll
  for (int ni = 0; ni < 4; ++ni) {
    long ccol = bn + wc * 64 + ni * 16 + (lane & 15);
    if (ccol >= Nn) continue;
    float bv = bias[ccol];
#pragma unroll
    for (int mi = 0; mi < 4; ++mi) {
#pragma unroll
      for (int reg = 0; reg < 4; ++reg) {
        long rrow = bm + wr * 64 + mi * 16 + (lane >> 4) * 4 + reg;
        if (rrow >= M) continue;
        float v = acc[mi][ni][reg] + bv;
        if (SILU) v = v / (1.f + __expf(-v));
        if (MODE == 0) {
          Cb[rrow * Nn + ccol] = f2bf(v);
        } else {
          Cf[rrow * (long)OUTD + ccol] = v;
          if (ccol < LL) Ci[rrow * (long)LL + ccol] = v;
          else           Cr[rrow * (long)LL + (ccol - LL)] = v;
        }
      }
    }
  }
}

extern "C" void kernel_launch(void* const* d_in, const int* in_sizes, int n_in,
                              void* d_out, int out_size, void* d_ws, size_t ws_size,
                              hipStream_t stream) {
  const float* h      = (const float*)d_in[0];
  const int*   idx    = (const int*)d_in[1];
  const float* W_pool = (const float*)d_in[2];
  const float* b_pool = (const float*)d_in[3];
  const float* W1     = (const float*)d_in[4];
  const float* b1     = (const float*)d_in[5];
  const float* W2     = (const float*)d_in[6];
  const float* b2     = (const float*)d_in[7];
  const float* W3     = (const float*)d_in[8];
  const float* b3     = (const float*)d_in[9];

  float* out   = (float*)d_out;
  float* out_i = out + (size_t)GG * OUTD;
  float* out_r = out_i + (size_t)GG * LL;

  char* ws = (char*)d_ws;
  size_t off = 0;
  auto alloc = [&](size_t bytes) {
    void* p = ws + off;
    off += (bytes + 255) & ~(size_t)255;
    return p;
  };
  u16* WpoolT = (u16*)alloc((size_t)DD * DD * 2);
  u16* W1T    = (u16*)alloc((size_t)HH * DD * 2);
  u16* W2T    = (u16*)alloc((size_t)HH * HH * 2);
  u16* W3T    = (u16*)alloc((size_t)OUTD * HH * 2);
  u16* hG     = (u16*)alloc((size_t)GG * DD * 2);
  u16* x1     = (u16*)alloc((size_t)GG * HH * 2);
  u16* x2     = (u16*)alloc((size_t)GG * HH * 2);
  int* offs   = (int*)alloc((GG + 1) * sizeof(int));
  float* PS_ss = (float*)alloc((size_t)GG * SLOTS_G * 256 * 4);
  float* PS_ah = (float*)alloc((size_t)GG * SLOTS_G * 256 * 4);

  // 1) weight transposes + graph offsets
  transpose_bf16<<<dim3(8, 8), 256, 0, stream>>>(W_pool, WpoolT, DD, DD);
  transpose_bf16<<<dim3(32, 8), 256, 0, stream>>>(W1, W1T, DD, HH);
  transpose_bf16<<<dim3(32, 32), 256, 0, stream>>>(W2, W2T, HH, HH);
  transpose_bf16<<<dim3(126, 32), 256, 0, stream>>>(W3, W3T, HH, OUTD);
  graph_offsets<<<(GG + 256) / 256, 256, 0, stream>>>(idx, offs);

  // 2) fused att-GEMM + segmented exp-sum pooling (reads h once)
  fused_pool<<<(NN + ROWS_PB - 1) / ROWS_PB, 512, 0, stream>>>(
      h, WpoolT, b_pool, idx, offs, PS_ss, PS_ah);
  finalize_pool<<<GG, 256, 0, stream>>>(PS_ss, PS_ah, offs, hG);

  // 3) MLP
  gemm_bt<1, 0, 64><<<dim3(8, 32), 256, 0, stream>>>(
      hG, W1T, b1, x1, nullptr, nullptr, nullptr, GG, HH, DD);
  gemm_bt<1, 0, 64><<<dim3(8, 32), 256, 0, stream>>>(
      x1, W2T, b2, x2, nullptr, nullptr, nullptr, GG, HH, HH);
  gemm_bt<0, 1, 32><<<dim3(32, 32), 256, 0, stream>>>(
      x2, W3T, b3, nullptr, out, out_i, out_r, GG, OUTD, HH);
}

// Round 6
// 286.966 us; speedup vs baseline: 1.9668x; 1.9668x over previous
//
#include <hip/hip_runtime.h>
#include <cstdint>
#include <cstddef>

#define NN 200000
#define DD 256
#define HH 1024
#define OUTD 4002
#define LL 2001
#define GG 4096

#define ROWS_PB 128
#define STEPS 8
#define SLOTS_L 8
#define SLOTS_G 4

typedef unsigned short u16;
typedef short short8 __attribute__((ext_vector_type(8)));
typedef float f32x4 __attribute__((ext_vector_type(4)));

static __device__ __forceinline__ u16 f2bf(float f) {
  uint32_t u = __float_as_uint(f);
  uint32_t r = (u + 0x7FFFu + ((u >> 16) & 1u)) >> 16;
  return (u16)r;
}
static __device__ __forceinline__ float bf2f(u16 b) {
  return __uint_as_float(((uint32_t)b) << 16);
}

static __device__ __forceinline__ void gld_lds16(const void* g, void* l) {
  __builtin_amdgcn_global_load_lds((const __attribute__((address_space(1))) void*)g,
                                   (__attribute__((address_space(3))) void*)l,
                                   16, 0, 0);
}

// Raw barrier: LDS ops flushed, but GLOBAL loads stay in flight across it.
static __device__ __forceinline__ void barrier_nodrain() {
  asm volatile("s_waitcnt lgkmcnt(0)" ::: "memory");
  __builtin_amdgcn_s_barrier();
  __builtin_amdgcn_sched_barrier(0);
}

// ---------------- transpose W (K x Nc fp32) -> WT (Nc x K bf16) ----------------
__global__ __launch_bounds__(256) void transpose_bf16(const float* __restrict__ W,
                                                      u16* __restrict__ WT,
                                                      int K, int Nc) {
  __shared__ float tile[32][33];
  int nt = blockIdx.x * 32, kt = blockIdx.y * 32;
  int tx = threadIdx.x & 31, ty = threadIdx.x >> 5;
#pragma unroll
  for (int i = 0; i < 4; ++i) {
    int k = kt + ty + i * 8, n = nt + tx;
    tile[ty + i * 8][tx] = (k < K && n < Nc) ? W[(size_t)k * Nc + n] : 0.f;
  }
  __syncthreads();
#pragma unroll
  for (int i = 0; i < 4; ++i) {
    int n = nt + ty + i * 8, k = kt + tx;
    if (n < Nc && k < K) WT[(size_t)n * K + k] = f2bf(tile[tx][ty + i * 8]);
  }
}

// ---------------- per-graph row offsets via binary search ----------------
__global__ void graph_offsets(const int* __restrict__ idx, int* __restrict__ offs) {
  int g = blockIdx.x * blockDim.x + threadIdx.x;
  if (g > GG) return;
  int lo = 0, hi = NN;
  while (lo < hi) {
    int mid = (lo + hi) >> 1;
    if (idx[mid] < g) lo = mid + 1; else hi = mid;
  }
  offs[g] = lo;
}

// ---------------- fused: att-GEMM + segmented exp-sum pooling ----------------
__global__ __launch_bounds__(512) void fused_pool(const float* __restrict__ h,
                                                  const u16* __restrict__ WT,
                                                  const float* __restrict__ bias,
                                                  const int* __restrict__ idx,
                                                  const int* __restrict__ offs,
                                                  float* __restrict__ PS_ss,
                                                  float* __restrict__ PS_ah) {
  __shared__ __align__(16) u16 At[2][16 * 256];   // 2 x 8KB
  __shared__ float accS[SLOTS_L * 256];           // 8KB
  __shared__ float accA[SLOTS_L * 256];           // 8KB
  __shared__ int lidx[ROWS_PB];

  const int tid = threadIdx.x;
  const int wave = tid >> 6, lane = tid & 63;
  const int rl = lane & 15, q = lane >> 4;
  const int b = blockIdx.x;
  const long row0 = (long)b * ROWS_PB;

  if (tid < ROWS_PB) {
    long r = row0 + tid;
    lidx[tid] = (r < NN) ? idx[r] : -1;
  }
  for (int i = tid; i < SLOTS_L * 256; i += 512) { accS[i] = 0.f; accA[i] = 0.f; }

  // B fragments (W_pool^T, L2-resident): features f0 = wave*32+rl, f1 = f0+16
  const int f0 = wave * 32 + rl, f1 = f0 + 16;
  short8 Bf0[8], Bf1[8];
  {
    const u16* wp0 = WT + (size_t)f0 * 256 + q * 8;
    const u16* wp1 = WT + (size_t)f1 * 256 + q * 8;
#pragma unroll
    for (int k0 = 0; k0 < 8; ++k0) {
      Bf0[k0] = *reinterpret_cast<const short8*>(wp0 + k0 * 32);
      Bf1[k0] = *reinterpret_cast<const short8*>(wp1 + k0 * 32);
    }
  }
  const float bv0 = bias[f0], bv1 = bias[f1];

  // staging mapping: thread -> row tr, elems te..te+7 (bf16, XOR-swizzled)
  const int tr = tid >> 5, te = (tid & 31) * 8;
  const int wbyte = tr * 512 + ((te * 2) ^ ((tr & 7) << 4));
  float4 pf0, pf1;
  auto issue = [&](int st) {
    long r = row0 + (long)st * 16 + tr;
    if (r >= NN) r = NN - 1;
    const float* p = h + r * 256 + te;
    pf0 = *reinterpret_cast<const float4*>(p);
    pf1 = *reinterpret_cast<const float4*>(p + 4);
  };
  auto commit = [&](int bufsel) {
    short8 w;
    w[0] = (short)f2bf(pf0.x); w[1] = (short)f2bf(pf0.y);
    w[2] = (short)f2bf(pf0.z); w[3] = (short)f2bf(pf0.w);
    w[4] = (short)f2bf(pf1.x); w[5] = (short)f2bf(pf1.y);
    w[6] = (short)f2bf(pf1.z); w[7] = (short)f2bf(pf1.w);
    *reinterpret_cast<short8*>((char*)&At[0][0] + bufsel * 8192 + wbyte) = w;
  };

  // hoisted LDS read offsets
  int afoff[8], hv0off[4], hv1off[4];
#pragma unroll
  for (int k0 = 0; k0 < 8; ++k0)
    afoff[k0] = rl * 512 + ((k0 * 64 + q * 16) ^ ((rl & 7) << 4));
#pragma unroll
  for (int reg = 0; reg < 4; ++reg) {
    int rloc = q * 4 + reg;
    hv0off[reg] = rloc * 512 + ((f0 * 2) ^ ((rloc & 7) << 4));
    hv1off[reg] = rloc * 512 + ((f1 * 2) ^ ((rloc & 7) << 4));
  }

  issue(0);
  commit(0);
  issue(1);
  barrier_nodrain();

  const int gfirst = lidx[0];
  int cur = -1;
  float ss0 = 0.f, ss1 = 0.f, ah0 = 0.f, ah1 = 0.f;

#pragma unroll
  for (int st = 0; st < STEPS; ++st) {
    const char* Ab = (const char*)&At[0][0] + (st & 1) * 8192;
    short8 af[8];
#pragma unroll
    for (int k0 = 0; k0 < 8; ++k0)
      af[k0] = *reinterpret_cast<const short8*>(Ab + afoff[k0]);
    f32x4 acc0 = {0.f, 0.f, 0.f, 0.f}, acc1 = {0.f, 0.f, 0.f, 0.f};
#pragma unroll
    for (int k0 = 0; k0 < 8; ++k0) {
      acc0 = __builtin_amdgcn_mfma_f32_16x16x32_bf16(af[k0], Bf0[k0], acc0, 0, 0, 0);
      acc1 = __builtin_amdgcn_mfma_f32_16x16x32_bf16(af[k0], Bf1[k0], acc1, 0, 0, 0);
    }
#pragma unroll
    for (int reg = 0; reg < 4; ++reg) {
      const int rloc = q * 4 + reg;
      const int gid = lidx[st * 16 + rloc];
      float z0 = acc0[reg] + bv0, z1 = acc1[reg] + bv1;
      float a0 = z0 / (1.f + __expf(-z0));
      float a1 = z1 / (1.f + __expf(-z1));
      float x0 = __expf(a0), x1 = __expf(a1);
      float hv0 = bf2f(*reinterpret_cast<const u16*>(Ab + hv0off[reg]));
      float hv1 = bf2f(*reinterpret_cast<const u16*>(Ab + hv1off[reg]));
      if (gid != cur) {
        if (cur >= 0) {
          int sl = cur - gfirst; if (sl >= SLOTS_L) sl = SLOTS_L - 1;
          atomicAdd(&accS[sl * 256 + f0], ss0);
          atomicAdd(&accA[sl * 256 + f0], ah0);
          atomicAdd(&accS[sl * 256 + f1], ss1);
          atomicAdd(&accA[sl * 256 + f1], ah1);
        }
        ss0 = ss1 = ah0 = ah1 = 0.f;
        cur = gid;
      }
      if (gid >= 0) {
        ss0 += x0; ah0 = __builtin_fmaf(x0, hv0, ah0);
        ss1 += x1; ah1 = __builtin_fmaf(x1, hv1, ah1);
      }
    }
    if (st + 1 < STEPS) {
      commit((st + 1) & 1);
      if (st + 2 < STEPS) issue(st + 2);
    }
    barrier_nodrain();
  }

  if (cur >= 0) {
    int sl = cur - gfirst; if (sl >= SLOTS_L) sl = SLOTS_L - 1;
    atomicAdd(&accS[sl * 256 + f0], ss0);
    atomicAdd(&accA[sl * 256 + f0], ah0);
    atomicAdd(&accS[sl * 256 + f1], ss1);
    atomicAdd(&accA[sl * 256 + f1], ah1);
  }
  __syncthreads();

  // write per-(graph, slot) partials (no atomics: slot unique per block)
  long lastrow = row0 + ROWS_PB - 1; if (lastrow >= NN) lastrow = NN - 1;
  const int glast = idx[lastrow];
  int gspan = glast - gfirst + 1; if (gspan > SLOTS_L) gspan = SLOTS_L;
  const int f = tid & 255, which = tid >> 8;
  for (int s = 0; s < gspan; ++s) {
    int g = gfirst + s;
    int osl = b - (offs[g] >> 7);
    if (osl < 0) osl = 0;
    if (osl >= SLOTS_G) osl = SLOTS_G - 1;
    float v = which ? accA[s * 256 + f] : accS[s * 256 + f];
    float* dst = which ? PS_ah : PS_ss;
    dst[((size_t)g * SLOTS_G + osl) * 256 + f] = v;
  }
}

// ---------------- finalize: hG = sum(AH)/sum(SS) ----------------
__global__ __launch_bounds__(256) void finalize_pool(const float* __restrict__ PS_ss,
                                                     const float* __restrict__ PS_ah,
                                                     const int* __restrict__ offs,
                                                     u16* __restrict__ hG) {
  int i = blockIdx.x * 256 + threadIdx.x;
  int g = i >> 8, f = i & 255;
  int s0 = offs[g], s1 = offs[g + 1];
  float o = 0.f;
  if (s1 > s0) {
    int b0 = s0 >> 7, b1 = (s1 - 1) >> 7;
    int nsl = b1 - b0 + 1; if (nsl > SLOTS_G) nsl = SLOTS_G;
    float ss = 0.f, ah = 0.f;
    for (int s = 0; s < nsl; ++s) {
      ss += PS_ss[((size_t)g * SLOTS_G + s) * 256 + f];
      ah += PS_ah[((size_t)g * SLOTS_G + s) * 256 + f];
    }
    o = ah / fmaxf(ss, 1e-12f);
  }
  hG[i] = f2bf(o);
}

// ------- bf16 MFMA GEMM: 512 thr / 8 waves (2x4), wave=64x32, counted-vmcnt dbuf -------
template <int SILU, int MODE, int BK>
__global__ __launch_bounds__(512) void gemm_bt(const u16* __restrict__ A,
                                               const u16* __restrict__ BT,
                                               const float* __restrict__ bias,
                                               u16* __restrict__ Cb,
                                               float* __restrict__ Cf,
                                               float* __restrict__ Ci,
                                               float* __restrict__ Cr,
                                               int M, int Nn, int K) {
  constexpr int NSUB = BK / 32;
  __shared__ __align__(16) u16 As[2][NSUB][128 * 32];
  __shared__ __align__(16) u16 Bs[2][NSUB][128 * 32];
  const int tid = threadIdx.x;
  const int wave = tid >> 6, lane = tid & 63;
  const int wr = wave >> 2, wc = wave & 3;  // 2 (M) x 4 (N)
  const long bm = (long)blockIdx.y * 128;
  const long bn = (long)blockIdx.x * 128;

  const f32x4 zero = {0.f, 0.f, 0.f, 0.f};
  f32x4 acc[4][2];
#pragma unroll
  for (int i = 0; i < 4; ++i)
#pragma unroll
    for (int j = 0; j < 2; ++j) acc[i][j] = zero;

  const int rg = lane >> 2;        // 0..15 staging row within wave's 16-row group
  const int kc = (lane & 3) * 8;   // staging k-chunk
  const int rl = lane & 15;
  const int kk = (lane >> 4) * 8;
  const int rbase = wave * 16;     // wave's staging row base (8 waves x 16 = 128)
  const int nt = K / BK;

  auto stage = [&](int t, int buf) {
    const long k0 = (long)t * BK;
#pragma unroll
    for (int s = 0; s < NSUB; ++s) {
      long rA = bm + rbase + rg; if (rA >= M) rA = M - 1;
      long rB = bn + rbase + rg; if (rB >= Nn) rB = Nn - 1;
      gld_lds16(A + rA * K + k0 + s * 32 + kc, &As[buf][s][rbase * 32]);
      gld_lds16(BT + rB * K + k0 + s * 32 + kc, &Bs[buf][s][rbase * 32]);
    }
  };

  stage(0, 0);
  for (int t = 0; t < nt; ++t) {
    const int buf = t & 1;
    if (t + 1 < nt) {
      stage(t + 1, buf ^ 1);
      if constexpr (NSUB == 1) {
        asm volatile("s_waitcnt vmcnt(2)" ::: "memory");  // t's loads done; t+1's in flight
      } else {
        asm volatile("s_waitcnt vmcnt(4)" ::: "memory");
      }
    } else {
      asm volatile("s_waitcnt vmcnt(0)" ::: "memory");
    }
    __builtin_amdgcn_s_barrier();
    __builtin_amdgcn_sched_barrier(0);

#pragma unroll
    for (int s = 0; s < NSUB; ++s) {
      short8 af[4], bfr[2];
#pragma unroll
      for (int mi = 0; mi < 4; ++mi)
        af[mi] = *reinterpret_cast<const short8*>(&As[buf][s][(wr * 64 + mi * 16 + rl) * 32 + kk]);
#pragma unroll
      for (int ni = 0; ni < 2; ++ni)
        bfr[ni] = *reinterpret_cast<const short8*>(&Bs[buf][s][(wc * 32 + ni * 16 + rl) * 32 + kk]);
#pragma unroll
      for (int mi = 0; mi < 4; ++mi)
#pragma unroll
        for (int ni = 0; ni < 2; ++ni)
          acc[mi][ni] = __builtin_amdgcn_mfma_f32_16x16x32_bf16(af[mi], bfr[ni], acc[mi][ni], 0, 0, 0);
    }

    asm volatile("s_waitcnt lgkmcnt(0)" ::: "memory");
    __builtin_amdgcn_s_barrier();
    __builtin_amdgcn_sched_barrier(0);
  }

#pragma unroll
  for (int ni = 0; ni < 2; ++ni) {
    long ccol = bn + wc * 32 + ni * 16 + rl;
    if (ccol >= Nn) continue;
    float bv = bias[ccol];
#pragma unroll
    for (int mi = 0; mi < 4; ++mi) {
#pragma unroll
      for (int reg = 0; reg < 4; ++reg) {
        long rrow = bm + wr * 64 + mi * 16 + (lane >> 4) * 4 + reg;
        if (rrow >= M) continue;
        float v = acc[mi][ni][reg] + bv;
        if (SILU) v = v / (1.f + __expf(-v));
        if (MODE == 0) {
          Cb[rrow * Nn + ccol] = f2bf(v);
        } else {
          Cf[rrow * (long)OUTD + ccol] = v;
          if (ccol < LL) Ci[rrow * (long)LL + ccol] = v;
          else           Cr[rrow * (long)LL + (ccol - LL)] = v;
        }
      }
    }
  }
}

extern "C" void kernel_launch(void* const* d_in, const int* in_sizes, int n_in,
                              void* d_out, int out_size, void* d_ws, size_t ws_size,
                              hipStream_t stream) {
  const float* h      = (const float*)d_in[0];
  const int*   idx    = (const int*)d_in[1];
  const float* W_pool = (const float*)d_in[2];
  const float* b_pool = (const float*)d_in[3];
  const float* W1     = (const float*)d_in[4];
  const float* b1     = (const float*)d_in[5];
  const float* W2     = (const float*)d_in[6];
  const float* b2     = (const float*)d_in[7];
  const float* W3     = (const float*)d_in[8];
  const float* b3     = (const float*)d_in[9];

  float* out   = (float*)d_out;
  float* out_i = out + (size_t)GG * OUTD;
  float* out_r = out_i + (size_t)GG * LL;

  char* ws = (char*)d_ws;
  size_t off = 0;
  auto alloc = [&](size_t bytes) {
    void* p = ws + off;
    off += (bytes + 255) & ~(size_t)255;
    return p;
  };
  u16* WpoolT = (u16*)alloc((size_t)DD * DD * 2);
  u16* W1T    = (u16*)alloc((size_t)HH * DD * 2);
  u16* W2T    = (u16*)alloc((size_t)HH * HH * 2);
  u16* W3T    = (u16*)alloc((size_t)OUTD * HH * 2);
  u16* hG     = (u16*)alloc((size_t)GG * DD * 2);
  u16* x1     = (u16*)alloc((size_t)GG * HH * 2);
  u16* x2     = (u16*)alloc((size_t)GG * HH * 2);
  int* offs   = (int*)alloc((GG + 1) * sizeof(int));
  float* PS_ss = (float*)alloc((size_t)GG * SLOTS_G * 256 * 4);
  float* PS_ah = (float*)alloc((size_t)GG * SLOTS_G * 256 * 4);

  // 1) weight transposes + graph offsets
  transpose_bf16<<<dim3(8, 8), 256, 0, stream>>>(W_pool, WpoolT, DD, DD);
  transpose_bf16<<<dim3(32, 8), 256, 0, stream>>>(W1, W1T, DD, HH);
  transpose_bf16<<<dim3(32, 32), 256, 0, stream>>>(W2, W2T, HH, HH);
  transpose_bf16<<<dim3(126, 32), 256, 0, stream>>>(W3, W3T, HH, OUTD);
  graph_offsets<<<(GG + 256) / 256, 256, 0, stream>>>(idx, offs);

  // 2) fused att-GEMM + segmented exp-sum pooling (reads h once)
  fused_pool<<<(NN + ROWS_PB - 1) / ROWS_PB, 512, 0, stream>>>(
      h, WpoolT, b_pool, idx, offs, PS_ss, PS_ah);
  finalize_pool<<<GG, 256, 0, stream>>>(PS_ss, PS_ah, offs, hG);

  // 3) MLP
  gemm_bt<1, 0, 64><<<dim3(8, 32), 512, 0, stream>>>(
      hG, W1T, b1, x1, nullptr, nullptr, nullptr, GG, HH, DD);
  gemm_bt<1, 0, 64><<<dim3(8, 32), 512, 0, stream>>>(
      x1, W2T, b2, x2, nullptr, nullptr, nullptr, GG, HH, HH);
  gemm_bt<0, 1, 32><<<dim3(32, 32), 512, 0, stream>>>(
      x2, W3T, b3, nullptr, out, out_i, out_r, GG, OUTD, HH);
}